// Round 1
// baseline (319.910 us; speedup 1.0000x reference)
//
#include <hip/hip_runtime.h>
#include <math.h>

#define N_G 2048
#define IMG_H 128
#define IMG_W 128

constexpr float FX = 128.0f;          // W / (2*tanfovx)
constexpr float FY = 128.0f;
constexpr float LIMX = 0.65f;         // 1.3 * tanfovx
constexpr float LIMY = 0.65f;
constexpr float ZNEAR_C = 0.2f;
constexpr float ALPHA_MIN_C = 1.0f / 255.0f;
constexpr float ALPHA_MAX_C = 0.99f;

// packed per-gaussian record: 12 floats (3 float4)
// [0]=px [1]=py [2]=conA [3]=conB | [4]=conC [5]=opac [6]=r [7]=g | [8]=b [9]=pcut [10,11]=pad

__global__ __launch_bounds__(256) void preprocess_kernel(
    const float* __restrict__ means3D, const float* __restrict__ opac_in,
    const float* __restrict__ cols, const float* __restrict__ scales,
    const float* __restrict__ rots, const float* __restrict__ vm,
    float* __restrict__ tz_out, float* __restrict__ unsorted)
{
    int i = blockIdx.x * blockDim.x + threadIdx.x;
    if (i >= N_G) return;

    float mx = means3D[3*i+0], my = means3D[3*i+1], mz = means3D[3*i+2];
    float q0 = rots[4*i+0], q1 = rots[4*i+1], q2 = rots[4*i+2], q3 = rots[4*i+3];
    float qn = 1.0f / sqrtf(q0*q0 + q1*q1 + q2*q2 + q3*q3);
    float r = q0*qn, x = q1*qn, y = q2*qn, z = q3*qn;

    float R00 = 1.0f - 2.0f*(y*y + z*z), R01 = 2.0f*(x*y - r*z), R02 = 2.0f*(x*z + r*y);
    float R10 = 2.0f*(x*y + r*z), R11 = 1.0f - 2.0f*(x*x + z*z), R12 = 2.0f*(y*z - r*x);
    float R20 = 2.0f*(x*z - r*y), R21 = 2.0f*(y*z + r*x), R22 = 1.0f - 2.0f*(x*x + y*y);

    float s0 = scales[3*i+0], s1 = scales[3*i+1], s2 = scales[3*i+2];
    // M[i][j] = R[i][j] * s[j]
    float M00 = R00*s0, M01 = R01*s1, M02 = R02*s2;
    float M10 = R10*s0, M11 = R11*s1, M12 = R12*s2;
    float M20 = R20*s0, M21 = R21*s1, M22 = R22*s2;

    // cov3D = M * M^T (symmetric)
    float C00 = M00*M00 + M01*M01 + M02*M02;
    float C01 = M00*M10 + M01*M11 + M02*M12;
    float C02 = M00*M20 + M01*M21 + M02*M22;
    float C11 = M10*M10 + M11*M11 + M12*M12;
    float C12 = M10*M20 + M11*M21 + M12*M22;
    float C22 = M20*M20 + M21*M21 + M22*M22;

    // view transform (row-major 4x4)
    float W00 = vm[0], W01 = vm[1], W02 = vm[2];
    float W10 = vm[4], W11 = vm[5], W12 = vm[6];
    float W20 = vm[8], W21 = vm[9], W22 = vm[10];
    float t0 = W00*mx + W01*my + W02*mz + vm[3];
    float t1 = W10*mx + W11*my + W12*mz + vm[7];
    float t2 = W20*mx + W21*my + W22*mz + vm[11];

    float tzv = t2;
    tz_out[i] = tzv;

    float invz = 1.0f / tzv;
    float txz = fminf(fmaxf(t0*invz, -LIMX), LIMX) * tzv;
    float tyz = fminf(fmaxf(t1*invz, -LIMY), LIMY) * tzv;

    float J00 = FX*invz, J02 = -FX*txz*invz*invz;
    float J11 = FY*invz, J12 = -FY*tyz*invz*invz;

    // T = J @ Wm  (2x3); J01 = J10 = 0
    float T00 = J00*W00 + J02*W20, T01 = J00*W01 + J02*W21, T02 = J00*W02 + J02*W22;
    float T10 = J11*W10 + J12*W20, T11 = J11*W11 + J12*W21, T12 = J11*W12 + J12*W22;

    // U = T @ C  (2x3), C symmetric
    float U00 = T00*C00 + T01*C01 + T02*C02;
    float U01 = T00*C01 + T01*C11 + T02*C12;
    float U02 = T00*C02 + T01*C12 + T02*C22;
    float U10 = T10*C00 + T11*C01 + T12*C02;
    float U11 = T10*C01 + T11*C11 + T12*C12;
    float U12 = T10*C02 + T11*C12 + T12*C22;

    float a = U00*T00 + U01*T01 + U02*T02 + 0.3f;
    float b = U00*T10 + U01*T11 + U02*T12;
    float c = U10*T10 + U11*T11 + U12*T12 + 0.3f;

    float det = a*c - b*b;
    bool valid = (det > 0.0f) && (tzv > ZNEAR_C);

    float px, py, cA, cB, cC, op, pcut;
    if (valid) {
        float invdet = 1.0f / det;
        cA = c * invdet;
        cB = -b * invdet;
        cC = a * invdet;
        px = FX * t0 * invz + (IMG_W - 1) * 0.5f;
        py = FY * t1 * invz + (IMG_H - 1) * 0.5f;
        op = opac_in[i];
        // contribute iff opac*exp(power) >= 1/255  <=>  power >= log(1/(255*opac))
        pcut = logf(ALPHA_MIN_C / op) - 1e-4f;  // small margin; exact test after exp
    } else {
        px = 0.0f; py = 0.0f; cA = 0.0f; cB = 0.0f; cC = 0.0f;
        op = 0.0f; pcut = 1e30f;  // power(=0) < pcut -> always culled
    }

    float* d = unsorted + 12*i;
    d[0] = px; d[1] = py; d[2] = cA; d[3] = cB;
    d[4] = cC; d[5] = op; d[6] = cols[3*i+0]; d[7] = cols[3*i+1];
    d[8] = cols[3*i+2]; d[9] = pcut; d[10] = 0.0f; d[11] = 0.0f;
}

__global__ __launch_bounds__(256) void rank_scatter_kernel(
    const float* __restrict__ tz, const float* __restrict__ unsorted,
    float* __restrict__ sorted_out)
{
    __shared__ float stz[N_G];
    int tid = threadIdx.x;
    int i = blockIdx.x * 256 + tid;
    for (int k = tid; k < N_G; k += 256) stz[k] = tz[k];
    __syncthreads();

    float myz = stz[i];
    int rank = 0;
    #pragma unroll 8
    for (int j = 0; j < N_G; ++j) {
        float zj = stz[j];
        rank += (zj < myz || (zj == myz && j < i)) ? 1 : 0;
    }

    const float4* u = (const float4*)unsorted;
    float4* s = (float4*)sorted_out;
    s[rank*3+0] = u[i*3+0];
    s[rank*3+1] = u[i*3+1];
    s[rank*3+2] = u[i*3+2];
}

#define CHUNK 256

__global__ __launch_bounds__(64) void raster_kernel(
    const float* __restrict__ sorted, const float* __restrict__ bg,
    float* __restrict__ out)
{
    __shared__ float4 sg[CHUNK*3];
    int lane = threadIdx.x;
    // 16x16 grid of 8x8 pixel tiles; one wave per tile
    int tx = blockIdx.x & 15, ty = blockIdx.x >> 4;
    int lx = lane & 7, ly = lane >> 3;
    int pxi = tx*8 + lx, pyi = ty*8 + ly;
    float fxp = (float)pxi, fyp = (float)pyi;

    float Tcur = 1.0f, Cr = 0.0f, Cg = 0.0f, Cb = 0.0f;
    const float4* src = (const float4*)sorted;

    for (int base = 0; base < N_G; base += CHUNK) {
        __syncthreads();
        for (int k = lane; k < CHUNK*3; k += 64)
            sg[k] = src[base*3 + k];
        __syncthreads();

        for (int gi = 0; gi < CHUNK; ++gi) {
            float4 d0 = sg[gi*3+0];   // px, py, cA, cB
            float4 d1 = sg[gi*3+1];   // cC, opac, r, g
            float dx = fxp - d0.x;
            float dy = fyp - d0.y;
            float power = -0.5f*(d0.z*dx*dx + d1.x*dy*dy) - d0.w*dx*dy;
            float4 d2 = sg[gi*3+2];   // b, pcut, pad, pad
            if (power > 0.0f || power < d2.y) continue;
            float alpha = fminf(ALPHA_MAX_C, d1.y * __expf(power));
            if (alpha < ALPHA_MIN_C) continue;  // exact reference test
            float w = Tcur * alpha;
            Cr += w * d1.z;
            Cg += w * d1.w;
            Cb += w * d2.x;
            Tcur *= (1.0f - alpha);
        }
        // whole wave done? (block == one wave, so this is uniform)
        if (__ballot(Tcur >= 1e-4f) == 0ull) break;
    }

    float bg0 = bg[0], bg1 = bg[1], bg2 = bg[2];
    int pidx = pyi * IMG_W + pxi;
    out[0*IMG_H*IMG_W + pidx] = Cr + Tcur * bg0;
    out[1*IMG_H*IMG_W + pidx] = Cg + Tcur * bg1;
    out[2*IMG_H*IMG_W + pidx] = Cb + Tcur * bg2;
}

extern "C" void kernel_launch(void* const* d_in, const int* in_sizes, int n_in,
                              void* d_out, int out_size, void* d_ws, size_t ws_size,
                              hipStream_t stream) {
    const float* means3D = (const float*)d_in[0];
    // d_in[1] = means2D: unused by the reference output
    const float* opac    = (const float*)d_in[2];
    const float* cols    = (const float*)d_in[3];
    const float* scales  = (const float*)d_in[4];
    const float* rots    = (const float*)d_in[5];
    const float* bg      = (const float*)d_in[6];
    const float* vm      = (const float*)d_in[7];
    float* out = (float*)d_out;

    float* tz       = (float*)d_ws;                 // 2048 floats
    float* unsorted = tz + N_G;                     // 2048*12 floats
    float* sorted   = unsorted + N_G*12;            // 2048*12 floats

    preprocess_kernel<<<8, 256, 0, stream>>>(means3D, opac, cols, scales, rots, vm,
                                             tz, unsorted);
    rank_scatter_kernel<<<8, 256, 0, stream>>>(tz, unsorted, sorted);
    raster_kernel<<<256, 64, 0, stream>>>(sorted, bg, out);
}

// Round 2
// 113.412 us; speedup vs baseline: 2.8208x; 2.8208x over previous
//
#include <hip/hip_runtime.h>
#include <math.h>

#define N_G 2048
#define IMG_H 128
#define IMG_W 128

constexpr float FX = 128.0f;          // W / (2*tanfovx)
constexpr float FY = 128.0f;
constexpr float LIMX = 0.65f;         // 1.3 * tanfovx
constexpr float LIMY = 0.65f;
constexpr float ZNEAR_C = 0.2f;
constexpr float ALPHA_MIN_C = 1.0f / 255.0f;
constexpr float ALPHA_MAX_C = 0.99f;

// packed per-gaussian record: 12 floats (3 float4)
// [0]=px [1]=py [2]=conA [3]=conB | [4]=conC [5]=opac [6]=r [7]=g | [8]=b [9]=pcut [10,11]=pad

__global__ __launch_bounds__(256) void preprocess_kernel(
    const float* __restrict__ means3D, const float* __restrict__ opac_in,
    const float* __restrict__ cols, const float* __restrict__ scales,
    const float* __restrict__ rots, const float* __restrict__ vm,
    float* __restrict__ tz_out, float* __restrict__ unsorted,
    unsigned int* __restrict__ bbox_out)
{
    int i = blockIdx.x * blockDim.x + threadIdx.x;
    if (i >= N_G) return;

    float mx = means3D[3*i+0], my = means3D[3*i+1], mz = means3D[3*i+2];
    float q0 = rots[4*i+0], q1 = rots[4*i+1], q2 = rots[4*i+2], q3 = rots[4*i+3];
    float qn = 1.0f / sqrtf(q0*q0 + q1*q1 + q2*q2 + q3*q3);
    float r = q0*qn, x = q1*qn, y = q2*qn, z = q3*qn;

    float R00 = 1.0f - 2.0f*(y*y + z*z), R01 = 2.0f*(x*y - r*z), R02 = 2.0f*(x*z + r*y);
    float R10 = 2.0f*(x*y + r*z), R11 = 1.0f - 2.0f*(x*x + z*z), R12 = 2.0f*(y*z - r*x);
    float R20 = 2.0f*(x*z - r*y), R21 = 2.0f*(y*z + r*x), R22 = 1.0f - 2.0f*(x*x + y*y);

    float s0 = scales[3*i+0], s1 = scales[3*i+1], s2 = scales[3*i+2];
    float M00 = R00*s0, M01 = R01*s1, M02 = R02*s2;
    float M10 = R10*s0, M11 = R11*s1, M12 = R12*s2;
    float M20 = R20*s0, M21 = R21*s1, M22 = R22*s2;

    float C00 = M00*M00 + M01*M01 + M02*M02;
    float C01 = M00*M10 + M01*M11 + M02*M12;
    float C02 = M00*M20 + M01*M21 + M02*M22;
    float C11 = M10*M10 + M11*M11 + M12*M12;
    float C12 = M10*M20 + M11*M21 + M12*M22;
    float C22 = M20*M20 + M21*M21 + M22*M22;

    float W00 = vm[0], W01 = vm[1], W02 = vm[2];
    float W10 = vm[4], W11 = vm[5], W12 = vm[6];
    float W20 = vm[8], W21 = vm[9], W22 = vm[10];
    float t0 = W00*mx + W01*my + W02*mz + vm[3];
    float t1 = W10*mx + W11*my + W12*mz + vm[7];
    float t2 = W20*mx + W21*my + W22*mz + vm[11];

    float tzv = t2;
    tz_out[i] = tzv;

    float invz = 1.0f / tzv;
    float txz = fminf(fmaxf(t0*invz, -LIMX), LIMX) * tzv;
    float tyz = fminf(fmaxf(t1*invz, -LIMY), LIMY) * tzv;

    float J00 = FX*invz, J02 = -FX*txz*invz*invz;
    float J11 = FY*invz, J12 = -FY*tyz*invz*invz;

    float T00 = J00*W00 + J02*W20, T01 = J00*W01 + J02*W21, T02 = J00*W02 + J02*W22;
    float T10 = J11*W10 + J12*W20, T11 = J11*W11 + J12*W21, T12 = J11*W12 + J12*W22;

    float U00 = T00*C00 + T01*C01 + T02*C02;
    float U01 = T00*C01 + T01*C11 + T02*C12;
    float U02 = T00*C02 + T01*C12 + T02*C22;
    float U10 = T10*C00 + T11*C01 + T12*C02;
    float U11 = T10*C01 + T11*C11 + T12*C12;
    float U12 = T10*C02 + T11*C12 + T12*C22;

    float a = U00*T00 + U01*T01 + U02*T02 + 0.3f;
    float b = U00*T10 + U01*T11 + U02*T12;
    float c = U10*T10 + U11*T11 + U12*T12 + 0.3f;

    float det = a*c - b*b;
    bool valid = (det > 0.0f) && (tzv > ZNEAR_C);

    float px, py, cA, cB, cC, op, pcut;
    unsigned int bb;
    if (valid) {
        float invdet = 1.0f / det;
        cA = c * invdet;
        cB = -b * invdet;
        cC = a * invdet;
        px = FX * t0 * invz + (IMG_W - 1) * 0.5f;
        py = FY * t1 * invz + (IMG_H - 1) * 0.5f;
        op = opac_in[i];
        pcut = logf(ALPHA_MIN_C / op) - 1e-4f;  // conservative margin; exact test after exp
        // exact per-axis extent of {power >= pcut}: ellipse d^T Con d <= -2*pcut,
        // Con = Sigma^-1 so (Con^-1)_00 = a, (Con^-1)_11 = c
        float hx = sqrtf(fmaxf(0.0f, -2.0f * pcut * a));
        float hy = sqrtf(fmaxf(0.0f, -2.0f * pcut * c));
        int ix0 = (int)floorf(px - hx), ix1 = (int)ceilf(px + hx);
        int iy0 = (int)floorf(py - hy), iy1 = (int)ceilf(py + hy);
        if (ix1 < 0 || ix0 > IMG_W-1 || iy1 < 0 || iy0 > IMG_H-1) {
            bb = 0x000000FFu;  // x0=255,x1=0 -> empty
        } else {
            unsigned int X0 = (unsigned int)max(0, ix0), X1 = (unsigned int)min(IMG_W-1, ix1);
            unsigned int Y0 = (unsigned int)max(0, iy0), Y1 = (unsigned int)min(IMG_H-1, iy1);
            bb = X0 | (X1 << 8) | (Y0 << 16) | (Y1 << 24);
        }
    } else {
        px = 0.0f; py = 0.0f; cA = 0.0f; cB = 0.0f; cC = 0.0f;
        op = 0.0f; pcut = 1e30f;
        bb = 0x000000FFu;      // empty bbox
    }

    float* d = unsorted + 12*i;
    d[0] = px; d[1] = py; d[2] = cA; d[3] = cB;
    d[4] = cC; d[5] = op; d[6] = cols[3*i+0]; d[7] = cols[3*i+1];
    d[8] = cols[3*i+2]; d[9] = pcut; d[10] = 0.0f; d[11] = 0.0f;
    bbox_out[i] = bb;
}

__global__ __launch_bounds__(64) void rank_scatter_kernel(
    const float* __restrict__ tz, const float* __restrict__ unsorted,
    const unsigned int* __restrict__ bbox_in,
    float* __restrict__ sorted_out, unsigned int* __restrict__ bbox_sorted)
{
    __shared__ float stz[N_G];
    int lane = threadIdx.x;
    int i = blockIdx.x * 64 + lane;
    for (int k = lane; k < N_G; k += 64) stz[k] = tz[k];
    __syncthreads();

    float myz = stz[i];
    int rank = 0;
    const float4* stz4 = (const float4*)stz;
    #pragma unroll 8
    for (int j = 0; j < N_G/4; ++j) {
        float4 z4 = stz4[j];
        int jb = j*4;
        rank += (z4.x < myz || (z4.x == myz && jb+0 < i)) ? 1 : 0;
        rank += (z4.y < myz || (z4.y == myz && jb+1 < i)) ? 1 : 0;
        rank += (z4.z < myz || (z4.z == myz && jb+2 < i)) ? 1 : 0;
        rank += (z4.w < myz || (z4.w == myz && jb+3 < i)) ? 1 : 0;
    }

    const float4* u = (const float4*)unsorted;
    float4* s = (float4*)sorted_out;
    s[rank*3+0] = u[i*3+0];
    s[rank*3+1] = u[i*3+1];
    s[rank*3+2] = u[i*3+2];
    bbox_sorted[rank] = bbox_in[i];
}

// one 64-thread wave per 8x8 pixel tile; 16x16 tiles
__global__ __launch_bounds__(64) void raster_kernel(
    const float* __restrict__ sorted, const unsigned int* __restrict__ bbox,
    const float* __restrict__ bg, float* __restrict__ out)
{
    __shared__ unsigned int sbb[N_G];
    __shared__ unsigned short sidx[N_G];
    int lane = threadIdx.x;
    int tx = blockIdx.x & 15, ty = blockIdx.x >> 4;

    // stage all bboxes into LDS (32 coalesced dword loads per lane)
    for (int k = lane; k < N_G; k += 64) sbb[k] = bbox[k];
    __syncthreads();

    // build depth-ordered hit list for this tile (stable ballot compaction)
    int tpx0 = tx*8, tpx1 = tx*8+7, tpy0 = ty*8, tpy1 = ty*8+7;
    int cnt = 0;
    for (int j0 = 0; j0 < N_G; j0 += 64) {
        unsigned int bb = sbb[j0 + lane];
        int x0 = bb & 0xFF, x1 = (bb >> 8) & 0xFF;
        int y0 = (bb >> 16) & 0xFF, y1 = (bb >> 24) & 0xFF;
        bool hit = (x0 <= tpx1) && (x1 >= tpx0) && (y0 <= tpy1) && (y1 >= tpy0);
        unsigned long long m = __ballot(hit);
        if (hit) {
            int pos = cnt + __popcll(m & ((1ull << lane) - 1ull));
            sidx[pos] = (unsigned short)(j0 + lane);
        }
        cnt += __popcll(m);
    }
    __syncthreads();

    int pxi = tpx0 + (lane & 7), pyi = tpy0 + (lane >> 3);
    float fxp = (float)pxi, fyp = (float)pyi;

    float Tcur = 1.0f, Cr = 0.0f, Cg = 0.0f, Cb = 0.0f;
    const float4* rec = (const float4*)sorted;

    for (int gi = 0; gi < cnt; ++gi) {
        int idx = sidx[gi];
        float4 d0 = rec[idx*3+0];   // px, py, cA, cB
        float4 d1 = rec[idx*3+1];   // cC, opac, r, g
        float4 d2 = rec[idx*3+2];   // b, pcut, pad, pad
        float dx = fxp - d0.x;
        float dy = fyp - d0.y;
        float power = -0.5f*(d0.z*dx*dx + d1.x*dy*dy) - d0.w*dx*dy;
        if (!(power > 0.0f || power < d2.y)) {
            float alpha = fminf(ALPHA_MAX_C, d1.y * __expf(power));
            if (alpha >= ALPHA_MIN_C) {
                float w = Tcur * alpha;
                Cr += w * d1.z;
                Cg += w * d1.w;
                Cb += w * d2.x;
                Tcur *= (1.0f - alpha);
            }
        }
        if ((gi & 7) == 7) {
            if (__ballot(Tcur >= 1e-4f) == 0ull) break;
        }
    }

    float bg0 = bg[0], bg1 = bg[1], bg2 = bg[2];
    int pidx = pyi * IMG_W + pxi;
    out[0*IMG_H*IMG_W + pidx] = Cr + Tcur * bg0;
    out[1*IMG_H*IMG_W + pidx] = Cg + Tcur * bg1;
    out[2*IMG_H*IMG_W + pidx] = Cb + Tcur * bg2;
}

extern "C" void kernel_launch(void* const* d_in, const int* in_sizes, int n_in,
                              void* d_out, int out_size, void* d_ws, size_t ws_size,
                              hipStream_t stream) {
    const float* means3D = (const float*)d_in[0];
    // d_in[1] = means2D: unused by the reference output
    const float* opac    = (const float*)d_in[2];
    const float* cols    = (const float*)d_in[3];
    const float* scales  = (const float*)d_in[4];
    const float* rots    = (const float*)d_in[5];
    const float* bg      = (const float*)d_in[6];
    const float* vm      = (const float*)d_in[7];
    float* out = (float*)d_out;

    float* tz            = (float*)d_ws;                    // 2048 floats
    float* unsorted      = tz + N_G;                        // 2048*12 floats
    float* sorted        = unsorted + N_G*12;               // 2048*12 floats
    unsigned int* bboxU  = (unsigned int*)(sorted + N_G*12);// 2048 u32
    unsigned int* bboxS  = bboxU + N_G;                     // 2048 u32

    preprocess_kernel<<<8, 256, 0, stream>>>(means3D, opac, cols, scales, rots, vm,
                                             tz, unsorted, bboxU);
    rank_scatter_kernel<<<32, 64, 0, stream>>>(tz, unsorted, bboxU, sorted, bboxS);
    raster_kernel<<<256, 64, 0, stream>>>(sorted, bboxS, bg, out);
}

// Round 3
// 53.750 us; speedup vs baseline: 5.9518x; 2.1100x over previous
//
#include <hip/hip_runtime.h>
#include <math.h>

#define N_G 2048
#define IMG_H 128
#define IMG_W 128

constexpr float FX = 128.0f;          // W / (2*tanfovx)
constexpr float FY = 128.0f;
constexpr float LIMX = 0.65f;         // 1.3 * tanfovx
constexpr float LIMY = 0.65f;
constexpr float ZNEAR_C = 0.2f;
constexpr float ALPHA_MIN_C = 1.0f / 255.0f;
constexpr float ALPHA_MAX_C = 0.99f;

// packed per-gaussian record: 12 floats (3 float4)
// [0]=px [1]=py [2]=conA [3]=conB | [4]=conC [5]=opac [6]=r [7]=g | [8]=b [9]=pcut [10,11]=pad

__global__ __launch_bounds__(256) void preprocess_kernel(
    const float* __restrict__ means3D, const float* __restrict__ opac_in,
    const float* __restrict__ cols, const float* __restrict__ scales,
    const float* __restrict__ rots, const float* __restrict__ vm,
    float* __restrict__ tz_out, float* __restrict__ unsorted,
    unsigned int* __restrict__ bbox_out)
{
    int i = blockIdx.x * blockDim.x + threadIdx.x;
    if (i >= N_G) return;

    float mx = means3D[3*i+0], my = means3D[3*i+1], mz = means3D[3*i+2];
    float q0 = rots[4*i+0], q1 = rots[4*i+1], q2 = rots[4*i+2], q3 = rots[4*i+3];
    float qn = 1.0f / sqrtf(q0*q0 + q1*q1 + q2*q2 + q3*q3);
    float r = q0*qn, x = q1*qn, y = q2*qn, z = q3*qn;

    float R00 = 1.0f - 2.0f*(y*y + z*z), R01 = 2.0f*(x*y - r*z), R02 = 2.0f*(x*z + r*y);
    float R10 = 2.0f*(x*y + r*z), R11 = 1.0f - 2.0f*(x*x + z*z), R12 = 2.0f*(y*z - r*x);
    float R20 = 2.0f*(x*z - r*y), R21 = 2.0f*(y*z + r*x), R22 = 1.0f - 2.0f*(x*x + y*y);

    float s0 = scales[3*i+0], s1 = scales[3*i+1], s2 = scales[3*i+2];
    float M00 = R00*s0, M01 = R01*s1, M02 = R02*s2;
    float M10 = R10*s0, M11 = R11*s1, M12 = R12*s2;
    float M20 = R20*s0, M21 = R21*s1, M22 = R22*s2;

    float C00 = M00*M00 + M01*M01 + M02*M02;
    float C01 = M00*M10 + M01*M11 + M02*M12;
    float C02 = M00*M20 + M01*M21 + M02*M22;
    float C11 = M10*M10 + M11*M11 + M12*M12;
    float C12 = M10*M20 + M11*M21 + M12*M22;
    float C22 = M20*M20 + M21*M21 + M22*M22;

    float W00 = vm[0], W01 = vm[1], W02 = vm[2];
    float W10 = vm[4], W11 = vm[5], W12 = vm[6];
    float W20 = vm[8], W21 = vm[9], W22 = vm[10];
    float t0 = W00*mx + W01*my + W02*mz + vm[3];
    float t1 = W10*mx + W11*my + W12*mz + vm[7];
    float t2 = W20*mx + W21*my + W22*mz + vm[11];

    float tzv = t2;
    tz_out[i] = tzv;

    float invz = 1.0f / tzv;
    float txz = fminf(fmaxf(t0*invz, -LIMX), LIMX) * tzv;
    float tyz = fminf(fmaxf(t1*invz, -LIMY), LIMY) * tzv;

    float J00 = FX*invz, J02 = -FX*txz*invz*invz;
    float J11 = FY*invz, J12 = -FY*tyz*invz*invz;

    float T00 = J00*W00 + J02*W20, T01 = J00*W01 + J02*W21, T02 = J00*W02 + J02*W22;
    float T10 = J11*W10 + J12*W20, T11 = J11*W11 + J12*W21, T12 = J11*W12 + J12*W22;

    float U00 = T00*C00 + T01*C01 + T02*C02;
    float U01 = T00*C01 + T01*C11 + T02*C12;
    float U02 = T00*C02 + T01*C12 + T02*C22;
    float U10 = T10*C00 + T11*C01 + T12*C02;
    float U11 = T10*C01 + T11*C11 + T12*C12;
    float U12 = T10*C02 + T11*C12 + T12*C22;

    float a = U00*T00 + U01*T01 + U02*T02 + 0.3f;
    float b = U00*T10 + U01*T11 + U02*T12;
    float c = U10*T10 + U11*T11 + U12*T12 + 0.3f;

    float det = a*c - b*b;
    bool valid = (det > 0.0f) && (tzv > ZNEAR_C);

    float px, py, cA, cB, cC, op, pcut;
    unsigned int bb;
    if (valid) {
        float invdet = 1.0f / det;
        cA = c * invdet;
        cB = -b * invdet;
        cC = a * invdet;
        px = FX * t0 * invz + (IMG_W - 1) * 0.5f;
        py = FY * t1 * invz + (IMG_H - 1) * 0.5f;
        op = opac_in[i];
        pcut = logf(ALPHA_MIN_C / op) - 1e-4f;  // conservative margin; exact test after exp
        // exact per-axis extent of {power >= pcut}: ellipse d^T Con d <= -2*pcut,
        // Con = Sigma^-1 so (Con^-1)_00 = a, (Con^-1)_11 = c
        float hx = sqrtf(fmaxf(0.0f, -2.0f * pcut * a));
        float hy = sqrtf(fmaxf(0.0f, -2.0f * pcut * c));
        int ix0 = (int)floorf(px - hx), ix1 = (int)ceilf(px + hx);
        int iy0 = (int)floorf(py - hy), iy1 = (int)ceilf(py + hy);
        if (ix1 < 0 || ix0 > IMG_W-1 || iy1 < 0 || iy0 > IMG_H-1) {
            bb = 0x000000FFu;  // x0=255,x1=0 -> empty
        } else {
            unsigned int X0 = (unsigned int)max(0, ix0), X1 = (unsigned int)min(IMG_W-1, ix1);
            unsigned int Y0 = (unsigned int)max(0, iy0), Y1 = (unsigned int)min(IMG_H-1, iy1);
            bb = X0 | (X1 << 8) | (Y0 << 16) | (Y1 << 24);
        }
    } else {
        px = 0.0f; py = 0.0f; cA = 0.0f; cB = 0.0f; cC = 0.0f;
        op = 0.0f; pcut = 1e30f;
        bb = 0x000000FFu;      // empty bbox
    }

    float* d = unsorted + 12*i;
    d[0] = px; d[1] = py; d[2] = cA; d[3] = cB;
    d[4] = cC; d[5] = op; d[6] = cols[3*i+0]; d[7] = cols[3*i+1];
    d[8] = cols[3*i+2]; d[9] = pcut; d[10] = 0.0f; d[11] = 0.0f;
    bbox_out[i] = bb;
}

// 64 blocks x 256 threads: block = (ib, jc); partial rank of i over j-chunk jc
__global__ __launch_bounds__(256) void rank_partial_kernel(
    const float* __restrict__ tz, unsigned short* __restrict__ partial)
{
    __shared__ float sz[256];
    int tid = threadIdx.x;
    int ib = blockIdx.x & 7;        // i-chunk
    int jc = blockIdx.x >> 3;       // j-chunk
    int i = ib*256 + tid;
    int jbase = jc*256;
    sz[tid] = tz[jbase + tid];
    float myz = tz[i];
    __syncthreads();

    int cnt = 0;
    const float4* sz4 = (const float4*)sz;
    #pragma unroll
    for (int j4 = 0; j4 < 64; ++j4) {
        float4 z = sz4[j4];
        int j = jbase + j4*4;
        cnt += (z.x < myz || (z.x == myz && j+0 < i)) ? 1 : 0;
        cnt += (z.y < myz || (z.y == myz && j+1 < i)) ? 1 : 0;
        cnt += (z.z < myz || (z.z == myz && j+2 < i)) ? 1 : 0;
        cnt += (z.w < myz || (z.w == myz && j+3 < i)) ? 1 : 0;
    }
    partial[jc*N_G + i] = (unsigned short)cnt;
}

// 8 blocks x 256 threads: sum partials -> rank, scatter record + bbox
__global__ __launch_bounds__(256) void scatter_kernel(
    const unsigned short* __restrict__ partial, const float* __restrict__ unsorted,
    const unsigned int* __restrict__ bbox_in,
    float* __restrict__ sorted_out, unsigned int* __restrict__ bbox_sorted)
{
    int i = blockIdx.x*256 + threadIdx.x;
    int rank = 0;
    #pragma unroll
    for (int jc = 0; jc < 8; ++jc) rank += partial[jc*N_G + i];

    const float4* u = (const float4*)unsorted;
    float4* s = (float4*)sorted_out;
    s[rank*3+0] = u[i*3+0];
    s[rank*3+1] = u[i*3+1];
    s[rank*3+2] = u[i*3+2];
    bbox_sorted[rank] = bbox_in[i];
}

// one 64-thread wave per 8x8 pixel tile; 16x16 tiles
__global__ __launch_bounds__(64) void raster_kernel(
    const float* __restrict__ sorted, const unsigned int* __restrict__ bbox,
    const float* __restrict__ bg, float* __restrict__ out)
{
    __shared__ unsigned int sbb[N_G];
    __shared__ unsigned short sidx[N_G];
    int lane = threadIdx.x;
    int tx = blockIdx.x & 15, ty = blockIdx.x >> 4;

    // stage all bboxes into LDS (32 coalesced dword loads per lane)
    for (int k = lane; k < N_G; k += 64) sbb[k] = bbox[k];
    __syncthreads();

    // build depth-ordered hit list for this tile (stable ballot compaction)
    int tpx0 = tx*8, tpx1 = tx*8+7, tpy0 = ty*8, tpy1 = ty*8+7;
    int cnt = 0;
    for (int j0 = 0; j0 < N_G; j0 += 64) {
        unsigned int bb = sbb[j0 + lane];
        int x0 = bb & 0xFF, x1 = (bb >> 8) & 0xFF;
        int y0 = (bb >> 16) & 0xFF, y1 = (bb >> 24) & 0xFF;
        bool hit = (x0 <= tpx1) && (x1 >= tpx0) && (y0 <= tpy1) && (y1 >= tpy0);
        unsigned long long m = __ballot(hit);
        if (hit) {
            int pos = cnt + __popcll(m & ((1ull << lane) - 1ull));
            sidx[pos] = (unsigned short)(j0 + lane);
        }
        cnt += __popcll(m);
    }
    __syncthreads();

    int pxi = tpx0 + (lane & 7), pyi = tpy0 + (lane >> 3);
    float fxp = (float)pxi, fyp = (float)pyi;

    float Tcur = 1.0f, Cr = 0.0f, Cg = 0.0f, Cb = 0.0f;
    const float4* rec = (const float4*)sorted;

    for (int gi = 0; gi < cnt; ++gi) {
        int idx = sidx[gi];
        float4 d0 = rec[idx*3+0];   // px, py, cA, cB
        float4 d1 = rec[idx*3+1];   // cC, opac, r, g
        float4 d2 = rec[idx*3+2];   // b, pcut, pad, pad
        float dx = fxp - d0.x;
        float dy = fyp - d0.y;
        float power = -0.5f*(d0.z*dx*dx + d1.x*dy*dy) - d0.w*dx*dy;
        if (!(power > 0.0f || power < d2.y)) {
            float alpha = fminf(ALPHA_MAX_C, d1.y * __expf(power));
            if (alpha >= ALPHA_MIN_C) {
                float w = Tcur * alpha;
                Cr += w * d1.z;
                Cg += w * d1.w;
                Cb += w * d2.x;
                Tcur *= (1.0f - alpha);
            }
        }
        if ((gi & 7) == 7) {
            if (__ballot(Tcur >= 1e-4f) == 0ull) break;
        }
    }

    float bg0 = bg[0], bg1 = bg[1], bg2 = bg[2];
    int pidx = pyi * IMG_W + pxi;
    out[0*IMG_H*IMG_W + pidx] = Cr + Tcur * bg0;
    out[1*IMG_H*IMG_W + pidx] = Cg + Tcur * bg1;
    out[2*IMG_H*IMG_W + pidx] = Cb + Tcur * bg2;
}

extern "C" void kernel_launch(void* const* d_in, const int* in_sizes, int n_in,
                              void* d_out, int out_size, void* d_ws, size_t ws_size,
                              hipStream_t stream) {
    const float* means3D = (const float*)d_in[0];
    // d_in[1] = means2D: unused by the reference output
    const float* opac    = (const float*)d_in[2];
    const float* cols    = (const float*)d_in[3];
    const float* scales  = (const float*)d_in[4];
    const float* rots    = (const float*)d_in[5];
    const float* bg      = (const float*)d_in[6];
    const float* vm      = (const float*)d_in[7];
    float* out = (float*)d_out;

    float* tz              = (float*)d_ws;                      // 2048 f32
    float* unsorted        = tz + N_G;                          // 2048*12 f32
    float* sorted          = unsorted + N_G*12;                 // 2048*12 f32
    unsigned int* bboxU    = (unsigned int*)(sorted + N_G*12);  // 2048 u32
    unsigned int* bboxS    = bboxU + N_G;                       // 2048 u32
    unsigned short* partial= (unsigned short*)(bboxS + N_G);    // 8*2048 u16

    preprocess_kernel<<<8, 256, 0, stream>>>(means3D, opac, cols, scales, rots, vm,
                                             tz, unsorted, bboxU);
    rank_partial_kernel<<<64, 256, 0, stream>>>(tz, partial);
    scatter_kernel<<<8, 256, 0, stream>>>(partial, unsorted, bboxU, sorted, bboxS);
    raster_kernel<<<256, 64, 0, stream>>>(sorted, bboxS, bg, out);
}

// Round 4
// 45.732 us; speedup vs baseline: 6.9953x; 1.1753x over previous
//
#include <hip/hip_runtime.h>
#include <math.h>

#define N_G 2048
#define IMG_H 128
#define IMG_W 128

constexpr float FX = 128.0f;          // W / (2*tanfovx)
constexpr float FY = 128.0f;
constexpr float LIMX = 0.65f;         // 1.3 * tanfovx
constexpr float LIMY = 0.65f;
constexpr float ZNEAR_C = 0.2f;
constexpr float ALPHA_MIN_C = 1.0f / 255.0f;
constexpr float ALPHA_MAX_C = 0.99f;

// packed per-gaussian record: 12 floats (3 float4)
// [0]=px [1]=py [2]=conA [3]=conB | [4]=conC [5]=opac [6]=r [7]=g | [8]=b [9]=pcut [10,11]=pad

__global__ __launch_bounds__(256) void preprocess_kernel(
    const float* __restrict__ means3D, const float* __restrict__ opac_in,
    const float* __restrict__ cols, const float* __restrict__ scales,
    const float* __restrict__ rots, const float* __restrict__ vm,
    float* __restrict__ tz_out, float* __restrict__ unsorted,
    unsigned int* __restrict__ bbox_out)
{
    int i = blockIdx.x * blockDim.x + threadIdx.x;
    if (i >= N_G) return;

    float mx = means3D[3*i+0], my = means3D[3*i+1], mz = means3D[3*i+2];
    float q0 = rots[4*i+0], q1 = rots[4*i+1], q2 = rots[4*i+2], q3 = rots[4*i+3];
    float qn = 1.0f / sqrtf(q0*q0 + q1*q1 + q2*q2 + q3*q3);
    float r = q0*qn, x = q1*qn, y = q2*qn, z = q3*qn;

    float R00 = 1.0f - 2.0f*(y*y + z*z), R01 = 2.0f*(x*y - r*z), R02 = 2.0f*(x*z + r*y);
    float R10 = 2.0f*(x*y + r*z), R11 = 1.0f - 2.0f*(x*x + z*z), R12 = 2.0f*(y*z - r*x);
    float R20 = 2.0f*(x*z - r*y), R21 = 2.0f*(y*z + r*x), R22 = 1.0f - 2.0f*(x*x + y*y);

    float s0 = scales[3*i+0], s1 = scales[3*i+1], s2 = scales[3*i+2];
    float M00 = R00*s0, M01 = R01*s1, M02 = R02*s2;
    float M10 = R10*s0, M11 = R11*s1, M12 = R12*s2;
    float M20 = R20*s0, M21 = R21*s1, M22 = R22*s2;

    float C00 = M00*M00 + M01*M01 + M02*M02;
    float C01 = M00*M10 + M01*M11 + M02*M12;
    float C02 = M00*M20 + M01*M21 + M02*M22;
    float C11 = M10*M10 + M11*M11 + M12*M12;
    float C12 = M10*M20 + M11*M21 + M12*M22;
    float C22 = M20*M20 + M21*M21 + M22*M22;

    float W00 = vm[0], W01 = vm[1], W02 = vm[2];
    float W10 = vm[4], W11 = vm[5], W12 = vm[6];
    float W20 = vm[8], W21 = vm[9], W22 = vm[10];
    float t0 = W00*mx + W01*my + W02*mz + vm[3];
    float t1 = W10*mx + W11*my + W12*mz + vm[7];
    float t2 = W20*mx + W21*my + W22*mz + vm[11];

    float tzv = t2;
    tz_out[i] = tzv;

    float invz = 1.0f / tzv;
    float txz = fminf(fmaxf(t0*invz, -LIMX), LIMX) * tzv;
    float tyz = fminf(fmaxf(t1*invz, -LIMY), LIMY) * tzv;

    float J00 = FX*invz, J02 = -FX*txz*invz*invz;
    float J11 = FY*invz, J12 = -FY*tyz*invz*invz;

    float T00 = J00*W00 + J02*W20, T01 = J00*W01 + J02*W21, T02 = J00*W02 + J02*W22;
    float T10 = J11*W10 + J12*W20, T11 = J11*W11 + J12*W21, T12 = J11*W12 + J12*W22;

    float U00 = T00*C00 + T01*C01 + T02*C02;
    float U01 = T00*C01 + T01*C11 + T02*C12;
    float U02 = T00*C02 + T01*C12 + T02*C22;
    float U10 = T10*C00 + T11*C01 + T12*C02;
    float U11 = T10*C01 + T11*C11 + T12*C12;
    float U12 = T10*C02 + T11*C12 + T12*C22;

    float a = U00*T00 + U01*T01 + U02*T02 + 0.3f;
    float b = U00*T10 + U01*T11 + U02*T12;
    float c = U10*T10 + U11*T11 + U12*T12 + 0.3f;

    float det = a*c - b*b;
    bool valid = (det > 0.0f) && (tzv > ZNEAR_C);

    float px, py, cA, cB, cC, op, pcut;
    unsigned int bb;
    if (valid) {
        float invdet = 1.0f / det;
        cA = c * invdet;
        cB = -b * invdet;
        cC = a * invdet;
        px = FX * t0 * invz + (IMG_W - 1) * 0.5f;
        py = FY * t1 * invz + (IMG_H - 1) * 0.5f;
        op = opac_in[i];
        pcut = logf(ALPHA_MIN_C / op) - 1e-4f;  // conservative margin; exact test after exp
        float hx = sqrtf(fmaxf(0.0f, -2.0f * pcut * a));
        float hy = sqrtf(fmaxf(0.0f, -2.0f * pcut * c));
        int ix0 = (int)floorf(px - hx), ix1 = (int)ceilf(px + hx);
        int iy0 = (int)floorf(py - hy), iy1 = (int)ceilf(py + hy);
        if (ix1 < 0 || ix0 > IMG_W-1 || iy1 < 0 || iy0 > IMG_H-1) {
            bb = 0x000000FFu;  // x0=255,x1=0 -> empty
        } else {
            unsigned int X0 = (unsigned int)max(0, ix0), X1 = (unsigned int)min(IMG_W-1, ix1);
            unsigned int Y0 = (unsigned int)max(0, iy0), Y1 = (unsigned int)min(IMG_H-1, iy1);
            bb = X0 | (X1 << 8) | (Y0 << 16) | (Y1 << 24);
        }
    } else {
        px = 0.0f; py = 0.0f; cA = 0.0f; cB = 0.0f; cC = 0.0f;
        op = 0.0f; pcut = 1e30f;
        bb = 0x000000FFu;      // empty bbox
    }

    float* d = unsorted + 12*i;
    d[0] = px; d[1] = py; d[2] = cA; d[3] = cB;
    d[4] = cC; d[5] = op; d[6] = cols[3*i+0]; d[7] = cols[3*i+1];
    d[8] = cols[3*i+2]; d[9] = pcut; d[10] = 0.0f; d[11] = 0.0f;
    bbox_out[i] = bb;
}

// 64 blocks x 256 threads: block = (ib, jc); partial rank of i over j-chunk jc
__global__ __launch_bounds__(256) void rank_partial_kernel(
    const float* __restrict__ tz, unsigned short* __restrict__ partial)
{
    __shared__ float sz[256];
    int tid = threadIdx.x;
    int ib = blockIdx.x & 7;        // i-chunk
    int jc = blockIdx.x >> 3;       // j-chunk
    int i = ib*256 + tid;
    int jbase = jc*256;
    sz[tid] = tz[jbase + tid];
    float myz = tz[i];
    __syncthreads();

    int cnt = 0;
    const float4* sz4 = (const float4*)sz;
    #pragma unroll
    for (int j4 = 0; j4 < 64; ++j4) {
        float4 z = sz4[j4];
        int j = jbase + j4*4;
        cnt += (z.x < myz || (z.x == myz && j+0 < i)) ? 1 : 0;
        cnt += (z.y < myz || (z.y == myz && j+1 < i)) ? 1 : 0;
        cnt += (z.z < myz || (z.z == myz && j+2 < i)) ? 1 : 0;
        cnt += (z.w < myz || (z.w == myz && j+3 < i)) ? 1 : 0;
    }
    partial[jc*N_G + i] = (unsigned short)cnt;
}

// 8 blocks x 256 threads: sum partials -> rank, scatter record + bbox
__global__ __launch_bounds__(256) void scatter_kernel(
    const unsigned short* __restrict__ partial, const float* __restrict__ unsorted,
    const unsigned int* __restrict__ bbox_in,
    float* __restrict__ sorted_out, unsigned int* __restrict__ bbox_sorted)
{
    int i = blockIdx.x*256 + threadIdx.x;
    int rank = 0;
    #pragma unroll
    for (int jc = 0; jc < 8; ++jc) rank += partial[jc*N_G + i];

    const float4* u = (const float4*)unsorted;
    float4* s = (float4*)sorted_out;
    s[rank*3+0] = u[i*3+0];
    s[rank*3+1] = u[i*3+1];
    s[rank*3+2] = u[i*3+2];
    bbox_sorted[rank] = bbox_in[i];
}

#define REC_CHUNK 128

// one 64-thread wave per 8x8 pixel tile; 16x16 tiles
__global__ __launch_bounds__(64) void raster_kernel(
    const float* __restrict__ sorted, const unsigned int* __restrict__ bbox,
    const float* __restrict__ bg, float* __restrict__ out)
{
    __shared__ unsigned int sbb[N_G];
    __shared__ unsigned short sidx[N_G];
    __shared__ float4 srec[REC_CHUNK*3];
    int lane = threadIdx.x;
    int tx = blockIdx.x & 15, ty = blockIdx.x >> 4;

    // stage all bboxes into LDS (8 coalesced dwordx4 loads per lane)
    {
        uint4* s4 = (uint4*)sbb;
        const uint4* b4 = (const uint4*)bbox;
        for (int k = lane; k < N_G/4; k += 64) s4[k] = b4[k];
    }
    __syncthreads();

    // build depth-ordered hit list for this tile (stable ballot compaction)
    int tpx0 = tx*8, tpx1 = tx*8+7, tpy0 = ty*8, tpy1 = ty*8+7;
    int cnt = 0;
    for (int j0 = 0; j0 < N_G; j0 += 64) {
        unsigned int bb = sbb[j0 + lane];
        int x0 = bb & 0xFF, x1 = (bb >> 8) & 0xFF;
        int y0 = (bb >> 16) & 0xFF, y1 = (bb >> 24) & 0xFF;
        bool hit = (x0 <= tpx1) && (x1 >= tpx0) && (y0 <= tpy1) && (y1 >= tpy0);
        unsigned long long m = __ballot(hit);
        if (hit) {
            int pos = cnt + __popcll(m & ((1ull << lane) - 1ull));
            sidx[pos] = (unsigned short)(j0 + lane);
        }
        cnt += __popcll(m);
    }
    __syncthreads();

    int pxi = tpx0 + (lane & 7), pyi = tpy0 + (lane >> 3);
    float fxp = (float)pxi, fyp = (float)pyi;

    float Tcur = 1.0f, Cr = 0.0f, Cg = 0.0f, Cb = 0.0f;
    const float4* rec = (const float4*)sorted;

    for (int base = 0; base < cnt; base += REC_CHUNK) {
        int m = cnt - base; if (m > REC_CHUNK) m = REC_CHUNK;
        // wave-parallel gather of m records (3 float4 each) into LDS
        for (int t = lane; t < m*3; t += 64) {
            int r = t / 3;
            int c = t - r*3;
            srec[t] = rec[(int)sidx[base + r]*3 + c];
        }
        __syncthreads();

        for (int gi = 0; gi < m; ++gi) {
            float4 d0 = srec[gi*3+0];   // px, py, cA, cB
            float4 d1 = srec[gi*3+1];   // cC, opac, r, g
            float4 d2 = srec[gi*3+2];   // b, pcut, pad, pad
            float dx = fxp - d0.x;
            float dy = fyp - d0.y;
            float power = -0.5f*(d0.z*dx*dx + d1.x*dy*dy) - d0.w*dx*dy;
            if (!(power > 0.0f || power < d2.y)) {
                float alpha = fminf(ALPHA_MAX_C, d1.y * __expf(power));
                if (alpha >= ALPHA_MIN_C) {
                    float w = Tcur * alpha;
                    Cr += w * d1.z;
                    Cg += w * d1.w;
                    Cb += w * d2.x;
                    Tcur *= (1.0f - alpha);
                }
            }
            if ((gi & 7) == 7) {
                if (__ballot(Tcur >= 1e-4f) == 0ull) { base = N_G; break; }
            }
        }
        if (base >= N_G) break;
        if (__ballot(Tcur >= 1e-4f) == 0ull) break;
        __syncthreads();  // before overwriting srec (uniform: block == one wave)
    }

    float bg0 = bg[0], bg1 = bg[1], bg2 = bg[2];
    int pidx = pyi * IMG_W + pxi;
    out[0*IMG_H*IMG_W + pidx] = Cr + Tcur * bg0;
    out[1*IMG_H*IMG_W + pidx] = Cg + Tcur * bg1;
    out[2*IMG_H*IMG_W + pidx] = Cb + Tcur * bg2;
}

extern "C" void kernel_launch(void* const* d_in, const int* in_sizes, int n_in,
                              void* d_out, int out_size, void* d_ws, size_t ws_size,
                              hipStream_t stream) {
    const float* means3D = (const float*)d_in[0];
    // d_in[1] = means2D: unused by the reference output
    const float* opac    = (const float*)d_in[2];
    const float* cols    = (const float*)d_in[3];
    const float* scales  = (const float*)d_in[4];
    const float* rots    = (const float*)d_in[5];
    const float* bg      = (const float*)d_in[6];
    const float* vm      = (const float*)d_in[7];
    float* out = (float*)d_out;

    float* tz              = (float*)d_ws;                      // 2048 f32
    float* unsorted        = tz + N_G;                          // 2048*12 f32
    float* sorted          = unsorted + N_G*12;                 // 2048*12 f32
    unsigned int* bboxU    = (unsigned int*)(sorted + N_G*12);  // 2048 u32
    unsigned int* bboxS    = bboxU + N_G;                       // 2048 u32
    unsigned short* partial= (unsigned short*)(bboxS + N_G);    // 8*2048 u16

    preprocess_kernel<<<8, 256, 0, stream>>>(means3D, opac, cols, scales, rots, vm,
                                             tz, unsorted, bboxU);
    rank_partial_kernel<<<64, 256, 0, stream>>>(tz, partial);
    scatter_kernel<<<8, 256, 0, stream>>>(partial, unsorted, bboxU, sorted, bboxS);
    raster_kernel<<<256, 64, 0, stream>>>(sorted, bboxS, bg, out);
}

// Round 5
// 37.242 us; speedup vs baseline: 8.5900x; 1.2280x over previous
//
#include <hip/hip_runtime.h>
#include <math.h>

#define N_G 2048
#define IMG_H 128
#define IMG_W 128

constexpr float FX = 128.0f;          // W / (2*tanfovx)
constexpr float FY = 128.0f;
constexpr float LIMX = 0.65f;         // 1.3 * tanfovx
constexpr float LIMY = 0.65f;
constexpr float ZNEAR_C = 0.2f;
constexpr float ALPHA_MIN_C = 1.0f / 255.0f;
constexpr float ALPHA_MAX_C = 0.99f;

struct VMc { float m[12]; };

// Full per-gaussian math. WANT_COLOR=false instantiations get colors DCE'd.
template <bool WANT_COLOR>
__device__ __forceinline__ void compute_g(
    int i,
    const float* __restrict__ means3D, const float* __restrict__ opac_in,
    const float* __restrict__ cols, const float* __restrict__ scales,
    const float* __restrict__ rots, const VMc& vm,
    float& px, float& py, float& cA, float& cB, float& cC,
    float& op, float& cr, float& cg, float& cb, float& pcut,
    float& tzv, unsigned int& bb)
{
    float mx = means3D[3*i+0], my = means3D[3*i+1], mz = means3D[3*i+2];
    float q0 = rots[4*i+0], q1 = rots[4*i+1], q2 = rots[4*i+2], q3 = rots[4*i+3];
    float qn = 1.0f / sqrtf(q0*q0 + q1*q1 + q2*q2 + q3*q3);
    float r = q0*qn, x = q1*qn, y = q2*qn, z = q3*qn;

    float R00 = 1.0f - 2.0f*(y*y + z*z), R01 = 2.0f*(x*y - r*z), R02 = 2.0f*(x*z + r*y);
    float R10 = 2.0f*(x*y + r*z), R11 = 1.0f - 2.0f*(x*x + z*z), R12 = 2.0f*(y*z - r*x);
    float R20 = 2.0f*(x*z - r*y), R21 = 2.0f*(y*z + r*x), R22 = 1.0f - 2.0f*(x*x + y*y);

    float s0 = scales[3*i+0], s1 = scales[3*i+1], s2 = scales[3*i+2];
    float M00 = R00*s0, M01 = R01*s1, M02 = R02*s2;
    float M10 = R10*s0, M11 = R11*s1, M12 = R12*s2;
    float M20 = R20*s0, M21 = R21*s1, M22 = R22*s2;

    float C00 = M00*M00 + M01*M01 + M02*M02;
    float C01 = M00*M10 + M01*M11 + M02*M12;
    float C02 = M00*M20 + M01*M21 + M02*M22;
    float C11 = M10*M10 + M11*M11 + M12*M12;
    float C12 = M10*M20 + M11*M21 + M12*M22;
    float C22 = M20*M20 + M21*M21 + M22*M22;

    float W00 = vm.m[0], W01 = vm.m[1], W02 = vm.m[2];
    float W10 = vm.m[4], W11 = vm.m[5], W12 = vm.m[6];
    float W20 = vm.m[8], W21 = vm.m[9], W22 = vm.m[10];
    float t0 = W00*mx + W01*my + W02*mz + vm.m[3];
    float t1 = W10*mx + W11*my + W12*mz + vm.m[7];
    float t2 = W20*mx + W21*my + W22*mz + vm.m[11];

    tzv = t2;
    float invz = 1.0f / tzv;
    float txz = fminf(fmaxf(t0*invz, -LIMX), LIMX) * tzv;
    float tyz = fminf(fmaxf(t1*invz, -LIMY), LIMY) * tzv;

    float J00 = FX*invz, J02 = -FX*txz*invz*invz;
    float J11 = FY*invz, J12 = -FY*tyz*invz*invz;

    float T00 = J00*W00 + J02*W20, T01 = J00*W01 + J02*W21, T02 = J00*W02 + J02*W22;
    float T10 = J11*W10 + J12*W20, T11 = J11*W11 + J12*W21, T12 = J11*W12 + J12*W22;

    float U00 = T00*C00 + T01*C01 + T02*C02;
    float U01 = T00*C01 + T01*C11 + T02*C12;
    float U02 = T00*C02 + T01*C12 + T02*C22;
    float U10 = T10*C00 + T11*C01 + T12*C02;
    float U11 = T10*C01 + T11*C11 + T12*C12;
    float U12 = T10*C02 + T11*C12 + T12*C22;

    float a = U00*T00 + U01*T01 + U02*T02 + 0.3f;
    float b = U00*T10 + U01*T11 + U02*T12;
    float c = U10*T10 + U11*T11 + U12*T12 + 0.3f;

    float det = a*c - b*b;
    bool valid = (det > 0.0f) && (tzv > ZNEAR_C);

    if (valid) {
        float invdet = 1.0f / det;
        cA = c * invdet;
        cB = -b * invdet;
        cC = a * invdet;
        px = FX * t0 * invz + (IMG_W - 1) * 0.5f;
        py = FY * t1 * invz + (IMG_H - 1) * 0.5f;
        op = opac_in[i];
        pcut = logf(ALPHA_MIN_C / op) - 1e-4f;  // conservative margin; exact test after exp
        // ellipse {power >= pcut}: d^T Con d <= -2*pcut; Con^-1 = [[a,b],[b,c]]
        float hx = sqrtf(fmaxf(0.0f, -2.0f * pcut * a));
        float hy = sqrtf(fmaxf(0.0f, -2.0f * pcut * c));
        int ix0 = (int)floorf(px - hx), ix1 = (int)ceilf(px + hx);
        int iy0 = (int)floorf(py - hy), iy1 = (int)ceilf(py + hy);
        if (ix1 < 0 || ix0 > IMG_W-1 || iy1 < 0 || iy0 > IMG_H-1) {
            bb = 0x000000FFu;  // empty
        } else {
            unsigned int X0 = (unsigned int)max(0, ix0), X1 = (unsigned int)min(IMG_W-1, ix1);
            unsigned int Y0 = (unsigned int)max(0, iy0), Y1 = (unsigned int)min(IMG_H-1, iy1);
            bb = X0 | (X1 << 8) | (Y0 << 16) | (Y1 << 24);
        }
    } else {
        px = 0.0f; py = 0.0f; cA = 0.0f; cB = 0.0f; cC = 0.0f;
        op = 0.0f; pcut = 1e30f;
        bb = 0x000000FFu;
    }
    if (WANT_COLOR) {
        cr = cols[3*i+0]; cg = cols[3*i+1]; cb = cols[3*i+2];
    } else {
        cr = 0.0f; cg = 0.0f; cb = 0.0f;
    }
}

// One block per 8x8 tile (16x16 tiles). 256 threads = 4 waves.
// Each block redundantly preprocesses all gaussians (tz+bbox), builds a
// depth-sorted hit list block-locally, recomputes full records for hits,
// and wave 0 composites the 64 pixels.
__global__ __launch_bounds__(256) void fused_kernel(
    const float* __restrict__ means3D, const float* __restrict__ opac_in,
    const float* __restrict__ cols, const float* __restrict__ scales,
    const float* __restrict__ rots, const float* __restrict__ bg,
    const float* __restrict__ vmp, float* __restrict__ out)
{
    __shared__ float s_tz[N_G];              // 8 KB
    __shared__ unsigned int s_bb[N_G];       // 8 KB
    __shared__ unsigned short stmp[4][512];  // 4 KB
    __shared__ unsigned short sidx[N_G];     // 4 KB
    __shared__ unsigned short ssort[N_G];    // 4 KB
    __shared__ float4 srec[256*3];           // 12 KB
    __shared__ int scnt[4], soff[5];

    int tid = threadIdx.x;
    int wave = tid >> 6, lane = tid & 63;
    int bx = blockIdx.x & 15, by = blockIdx.x >> 4;
    int tpx0 = bx*8, tpy0 = by*8;

    VMc vm;
    #pragma unroll
    for (int k = 0; k < 12; ++k) vm.m[k] = vmp[k];

    // ---- Phase A: tz + bbox for all gaussians ----
    for (int g = tid; g < N_G; g += 256) {
        float px,py,cA,cB,cC,op,cr,cg,cb,pcut,tzv; unsigned int bb;
        compute_g<false>(g, means3D, opac_in, cols, scales, rots, vm,
                         px,py,cA,cB,cC,op,cr,cg,cb,pcut,tzv,bb);
        s_tz[g] = tzv;
        s_bb[g] = bb;
    }
    __syncthreads();

    // ---- Phase B: per-wave stable compaction of tile hits ----
    int c = 0;
    for (int r = 0; r < 8; ++r) {
        int j = wave*512 + r*64 + lane;
        unsigned int bb = s_bb[j];
        int x0 = bb & 0xFF, x1 = (bb >> 8) & 0xFF;
        int y0 = (bb >> 16) & 0xFF, y1 = (bb >> 24) & 0xFF;
        bool hit = (x0 <= tpx0+7) && (x1 >= tpx0) && (y0 <= tpy0+7) && (y1 >= tpy0);
        unsigned long long m = __ballot(hit);
        if (hit) stmp[wave][c + __popcll(m & ((1ull << lane) - 1ull))] = (unsigned short)j;
        c += __popcll(m);
    }
    if (lane == 0) scnt[wave] = c;
    __syncthreads();
    if (tid == 0) { soff[0] = 0; for (int w = 0; w < 4; ++w) soff[w+1] = soff[w] + scnt[w]; }
    __syncthreads();
    int cnt = soff[4];
    for (int w = 0; w < 4; ++w)
        for (int k = tid; k < scnt[w]; k += 256)
            sidx[soff[w] + k] = stmp[w][k];
    __syncthreads();

    // ---- Phase C: rank-sort hits by (tz, idx); positive-float bits order = float order ----
    for (int t = tid; t < cnt; t += 256) {
        int idt = sidx[t];
        unsigned int kz = __float_as_uint(s_tz[idt]);
        int rank = 0;
        for (int u = 0; u < cnt; ++u) {           // uniform u -> broadcast LDS reads
            int idu = sidx[u];
            unsigned int zu = __float_as_uint(s_tz[idu]);
            rank += (zu < kz || (zu == kz && idu < idt)) ? 1 : 0;
        }
        ssort[rank] = (unsigned short)idt;
    }
    __syncthreads();

    // ---- Phase D: recompute hit records in chunks; wave 0 composites ----
    float Tcur = 1.0f, Cr = 0.0f, Cg = 0.0f, Cb = 0.0f;
    int pxi = tpx0 + (lane & 7), pyi = tpy0 + (lane >> 3);
    float fxp = (float)pxi, fyp = (float)pyi;

    for (int base = 0; base < cnt; base += 256) {
        int m = cnt - base; if (m > 256) m = 256;
        if (tid < m) {
            int g = ssort[base + tid];
            float px,py,cA,cB,cC,op,cr,cg,cb,pcut,tzv; unsigned int bb;
            compute_g<true>(g, means3D, opac_in, cols, scales, rots, vm,
                            px,py,cA,cB,cC,op,cr,cg,cb,pcut,tzv,bb);
            srec[tid*3+0] = make_float4(px, py, cA, cB);
            srec[tid*3+1] = make_float4(cC, op, cr, cg);
            srec[tid*3+2] = make_float4(cb, pcut, 0.0f, 0.0f);
        }
        __syncthreads();

        if (wave == 0) {
            for (int gi = 0; gi < m; ++gi) {
                float4 d0 = srec[gi*3+0];   // px, py, cA, cB
                float4 d1 = srec[gi*3+1];   // cC, opac, r, g
                float4 d2 = srec[gi*3+2];   // b, pcut, -, -
                float dx = fxp - d0.x;
                float dy = fyp - d0.y;
                float power = -0.5f*(d0.z*dx*dx + d1.x*dy*dy) - d0.w*dx*dy;
                if (!(power > 0.0f || power < d2.y)) {
                    float alpha = fminf(ALPHA_MAX_C, d1.y * __expf(power));
                    if (alpha >= ALPHA_MIN_C) {
                        float w = Tcur * alpha;
                        Cr += w * d1.z;
                        Cg += w * d1.w;
                        Cb += w * d2.x;
                        Tcur *= (1.0f - alpha);
                    }
                }
                if ((gi & 7) == 7) {
                    if (__ballot(Tcur >= 1e-4f) == 0ull) break;   // wave-uniform
                }
            }
        }
        // block-uniform early exit; also the barrier protecting srec overwrite
        int alive = __syncthreads_count((tid < 64) && (Tcur >= 1e-4f));
        if (alive == 0) break;
    }

    if (wave == 0) {
        float bg0 = bg[0], bg1 = bg[1], bg2 = bg[2];
        int pidx = pyi * IMG_W + pxi;
        out[0*IMG_H*IMG_W + pidx] = Cr + Tcur * bg0;
        out[1*IMG_H*IMG_W + pidx] = Cg + Tcur * bg1;
        out[2*IMG_H*IMG_W + pidx] = Cb + Tcur * bg2;
    }
}

extern "C" void kernel_launch(void* const* d_in, const int* in_sizes, int n_in,
                              void* d_out, int out_size, void* d_ws, size_t ws_size,
                              hipStream_t stream) {
    const float* means3D = (const float*)d_in[0];
    // d_in[1] = means2D: unused by the reference output
    const float* opac    = (const float*)d_in[2];
    const float* cols    = (const float*)d_in[3];
    const float* scales  = (const float*)d_in[4];
    const float* rots    = (const float*)d_in[5];
    const float* bg      = (const float*)d_in[6];
    const float* vm      = (const float*)d_in[7];
    float* out = (float*)d_out;

    fused_kernel<<<256, 256, 0, stream>>>(means3D, opac, cols, scales, rots, bg, vm, out);
}

// Round 6
// 19.574 us; speedup vs baseline: 16.3436x; 1.9026x over previous
//
#include <hip/hip_runtime.h>
#include <math.h>

#define N_G 2048
#define IMG_H 128
#define IMG_W 128

constexpr float FX = 128.0f;          // W / (2*tanfovx)
constexpr float FY = 128.0f;
constexpr float LIMX = 0.65f;         // 1.3 * tanfovx
constexpr float LIMY = 0.65f;
constexpr float ZNEAR_C = 0.2f;
constexpr float ALPHA_MIN_C = 1.0f / 255.0f;
constexpr float ALPHA_MAX_C = 0.99f;

struct VMc { float m[12]; };

// Full per-gaussian math. WANT_COLOR=false instantiations get colors DCE'd.
template <bool WANT_COLOR>
__device__ __forceinline__ void compute_g(
    int i,
    const float* __restrict__ means3D, const float* __restrict__ opac_in,
    const float* __restrict__ cols, const float* __restrict__ scales,
    const float* __restrict__ rots, const VMc& vm,
    float& px, float& py, float& cA, float& cB, float& cC,
    float& op, float& cr, float& cg, float& cb, float& pcut,
    float& tzv, unsigned int& bb)
{
    float mx = means3D[3*i+0], my = means3D[3*i+1], mz = means3D[3*i+2];
    float q0 = rots[4*i+0], q1 = rots[4*i+1], q2 = rots[4*i+2], q3 = rots[4*i+3];
    float qn = 1.0f / sqrtf(q0*q0 + q1*q1 + q2*q2 + q3*q3);
    float r = q0*qn, x = q1*qn, y = q2*qn, z = q3*qn;

    float R00 = 1.0f - 2.0f*(y*y + z*z), R01 = 2.0f*(x*y - r*z), R02 = 2.0f*(x*z + r*y);
    float R10 = 2.0f*(x*y + r*z), R11 = 1.0f - 2.0f*(x*x + z*z), R12 = 2.0f*(y*z - r*x);
    float R20 = 2.0f*(x*z - r*y), R21 = 2.0f*(y*z + r*x), R22 = 1.0f - 2.0f*(x*x + y*y);

    float s0 = scales[3*i+0], s1 = scales[3*i+1], s2 = scales[3*i+2];
    float M00 = R00*s0, M01 = R01*s1, M02 = R02*s2;
    float M10 = R10*s0, M11 = R11*s1, M12 = R12*s2;
    float M20 = R20*s0, M21 = R21*s1, M22 = R22*s2;

    float C00 = M00*M00 + M01*M01 + M02*M02;
    float C01 = M00*M10 + M01*M11 + M02*M12;
    float C02 = M00*M20 + M01*M21 + M02*M22;
    float C11 = M10*M10 + M11*M11 + M12*M12;
    float C12 = M10*M20 + M11*M21 + M12*M22;
    float C22 = M20*M20 + M21*M21 + M22*M22;

    float W00 = vm.m[0], W01 = vm.m[1], W02 = vm.m[2];
    float W10 = vm.m[4], W11 = vm.m[5], W12 = vm.m[6];
    float W20 = vm.m[8], W21 = vm.m[9], W22 = vm.m[10];
    float t0 = W00*mx + W01*my + W02*mz + vm.m[3];
    float t1 = W10*mx + W11*my + W12*mz + vm.m[7];
    float t2 = W20*mx + W21*my + W22*mz + vm.m[11];

    tzv = t2;
    float invz = 1.0f / tzv;
    float txz = fminf(fmaxf(t0*invz, -LIMX), LIMX) * tzv;
    float tyz = fminf(fmaxf(t1*invz, -LIMY), LIMY) * tzv;

    float J00 = FX*invz, J02 = -FX*txz*invz*invz;
    float J11 = FY*invz, J12 = -FY*tyz*invz*invz;

    float T00 = J00*W00 + J02*W20, T01 = J00*W01 + J02*W21, T02 = J00*W02 + J02*W22;
    float T10 = J11*W10 + J12*W20, T11 = J11*W11 + J12*W21, T12 = J11*W12 + J12*W22;

    float U00 = T00*C00 + T01*C01 + T02*C02;
    float U01 = T00*C01 + T01*C11 + T02*C12;
    float U02 = T00*C02 + T01*C12 + T02*C22;
    float U10 = T10*C00 + T11*C01 + T12*C02;
    float U11 = T10*C01 + T11*C11 + T12*C12;
    float U12 = T10*C02 + T11*C12 + T12*C22;

    float a = U00*T00 + U01*T01 + U02*T02 + 0.3f;
    float b = U00*T10 + U01*T11 + U02*T12;
    float c = U10*T10 + U11*T11 + U12*T12 + 0.3f;

    float det = a*c - b*b;
    bool valid = (det > 0.0f) && (tzv > ZNEAR_C);

    if (valid) {
        float invdet = 1.0f / det;
        cA = c * invdet;
        cB = -b * invdet;
        cC = a * invdet;
        px = FX * t0 * invz + (IMG_W - 1) * 0.5f;
        py = FY * t1 * invz + (IMG_H - 1) * 0.5f;
        op = opac_in[i];
        pcut = logf(ALPHA_MIN_C / op) - 1e-4f;  // conservative margin; exact test after exp
        // ellipse {power >= pcut}: d^T Con d <= -2*pcut; Con^-1 = [[a,b],[b,c]]
        float hx = sqrtf(fmaxf(0.0f, -2.0f * pcut * a));
        float hy = sqrtf(fmaxf(0.0f, -2.0f * pcut * c));
        int ix0 = (int)floorf(px - hx), ix1 = (int)ceilf(px + hx);
        int iy0 = (int)floorf(py - hy), iy1 = (int)ceilf(py + hy);
        if (ix1 < 0 || ix0 > IMG_W-1 || iy1 < 0 || iy0 > IMG_H-1) {
            bb = 0x000000FFu;  // empty
        } else {
            unsigned int X0 = (unsigned int)max(0, ix0), X1 = (unsigned int)min(IMG_W-1, ix1);
            unsigned int Y0 = (unsigned int)max(0, iy0), Y1 = (unsigned int)min(IMG_H-1, iy1);
            bb = X0 | (X1 << 8) | (Y0 << 16) | (Y1 << 24);
        }
    } else {
        px = 0.0f; py = 0.0f; cA = 0.0f; cB = 0.0f; cC = 0.0f;
        op = 0.0f; pcut = 1e30f;
        bb = 0x000000FFu;
    }
    if (WANT_COLOR) {
        cr = cols[3*i+0]; cg = cols[3*i+1]; cb = cols[3*i+2];
    } else {
        cr = 0.0f; cg = 0.0f; cb = 0.0f;
    }
}

#define NTHREADS 512
#define NWAVES 8

// One block per 8x8 tile (16x16 tiles). 512 threads = 8 waves.
// A: all gaussians tz+bbox (redundant per block, parallel across blocks)
// B: per-wave stable ballot compaction of tile hits + cross-wave prefix
// C: wave-parallel rank sort of hits by packed (tz_bits, idx) 64-bit key
// D: recompute hit records; 8-way segmented compositing + wave-0 combine
__global__ __launch_bounds__(NTHREADS) void fused_kernel(
    const float* __restrict__ means3D, const float* __restrict__ opac_in,
    const float* __restrict__ cols, const float* __restrict__ scales,
    const float* __restrict__ rots, const float* __restrict__ bg,
    const float* __restrict__ vmp, float* __restrict__ out)
{
    __shared__ float s_tz[N_G];                    // 8 KB
    __shared__ unsigned int s_bb[N_G];             // 8 KB
    __shared__ unsigned short stmp[NWAVES][256];   // 4 KB
    __shared__ unsigned short sidx[N_G];           // 4 KB
    __shared__ unsigned long long skey[N_G];       // 16 KB
    __shared__ unsigned short ssort[N_G];          // 4 KB
    __shared__ float4 srec[NTHREADS*3];            // 24 KB
    __shared__ float4 scomb[NWAVES*64];            // 8 KB
    __shared__ int scnt[NWAVES], soff[NWAVES+1];

    int tid = threadIdx.x;
    int wave = tid >> 6, lane = tid & 63;
    int bx = blockIdx.x & 15, by = blockIdx.x >> 4;
    int tpx0 = bx*8, tpy0 = by*8;

    VMc vm;
    #pragma unroll
    for (int k = 0; k < 12; ++k) vm.m[k] = vmp[k];

    // ---- Phase A: tz + bbox for all gaussians ----
    for (int g = tid; g < N_G; g += NTHREADS) {
        float px,py,cA,cB,cC,op,cr,cg,cb,pcut,tzv; unsigned int bb;
        compute_g<false>(g, means3D, opac_in, cols, scales, rots, vm,
                         px,py,cA,cB,cC,op,cr,cg,cb,pcut,tzv,bb);
        s_tz[g] = tzv;
        s_bb[g] = bb;
    }
    __syncthreads();

    // ---- Phase B: per-wave stable compaction of tile hits ----
    int c = 0;
    #pragma unroll
    for (int r = 0; r < N_G/NTHREADS; ++r) {   // 4 rounds of 64 per wave
        int j = wave*(N_G/NWAVES) + r*64 + lane;
        unsigned int bb = s_bb[j];
        int x0 = bb & 0xFF, x1 = (bb >> 8) & 0xFF;
        int y0 = (bb >> 16) & 0xFF, y1 = (bb >> 24) & 0xFF;
        bool hit = (x0 <= tpx0+7) && (x1 >= tpx0) && (y0 <= tpy0+7) && (y1 >= tpy0);
        unsigned long long m = __ballot(hit);
        if (hit) stmp[wave][c + __popcll(m & ((1ull << lane) - 1ull))] = (unsigned short)j;
        c += __popcll(m);
    }
    if (lane == 0) scnt[wave] = c;
    __syncthreads();
    if (tid == 0) { soff[0] = 0; for (int w = 0; w < NWAVES; ++w) soff[w+1] = soff[w] + scnt[w]; }
    __syncthreads();
    int cnt = soff[NWAVES];
    for (int w = 0; w < NWAVES; ++w) {
        int o = soff[w], n = scnt[w];
        for (int k = tid; k < n; k += NTHREADS) sidx[o + k] = stmp[w][k];
    }
    __syncthreads();

    // ---- build compact 64-bit sort keys: (tz_bits << 16) | idx ----
    for (int t = tid; t < cnt; t += NTHREADS) {
        int id = sidx[t];
        skey[t] = ((unsigned long long)__float_as_uint(s_tz[id]) << 16) | (unsigned int)id;
    }
    __syncthreads();

    // ---- Phase C: wave-parallel rank sort ----
    for (int t = wave; t < cnt; t += NWAVES) {
        unsigned long long key_t = skey[t];     // broadcast read
        int rank = 0;
        for (int u0 = 0; u0 < cnt; u0 += 64) {
            int u = u0 + lane;
            bool p = (u < cnt) && (skey[u] < key_t);
            rank += __popcll(__ballot(p));
        }
        if (lane == 0) ssort[rank] = (unsigned short)(key_t & 0xFFFFull);
    }
    __syncthreads();

    // ---- Phase D: chunks of 512 records; 8-way segmented composite ----
    int pxi = tpx0 + (lane & 7), pyi = tpy0 + (lane >> 3);
    float fxp = (float)pxi, fyp = (float)pyi;

    // wave-0 per-pixel global accumulators
    float Tg = 1.0f, Crg = 0.0f, Cgg = 0.0f, Cbg = 0.0f;

    for (int base = 0; base < cnt; base += NTHREADS) {
        int m = cnt - base; if (m > NTHREADS) m = NTHREADS;
        if (tid < m) {
            int g = ssort[base + tid];
            float px,py,cA,cB,cC,op,cr,cg,cb,pcut,tzv; unsigned int bb;
            compute_g<true>(g, means3D, opac_in, cols, scales, rots, vm,
                            px,py,cA,cB,cC,op,cr,cg,cb,pcut,tzv,bb);
            srec[tid*3+0] = make_float4(px, py, cA, cB);
            srec[tid*3+1] = make_float4(cC, op, cr, cg);
            srec[tid*3+2] = make_float4(cb, pcut, 0.0f, 0.0f);
        }
        __syncthreads();

        // segment [w*L, min(m,(w+1)*L)) for wave w; each lane = one pixel
        int L = (m + NWAVES - 1) / NWAVES;
        int g0 = wave * L, g1 = min(m, g0 + L);
        float Ts = 1.0f, Crs = 0.0f, Cgs = 0.0f, Cbs = 0.0f;
        for (int gi = g0; gi < g1; ++gi) {
            float4 d0 = srec[gi*3+0];   // px, py, cA, cB
            float4 d1 = srec[gi*3+1];   // cC, opac, r, g
            float4 d2 = srec[gi*3+2];   // b, pcut, -, -
            float dx = fxp - d0.x;
            float dy = fyp - d0.y;
            float power = -0.5f*(d0.z*dx*dx + d1.x*dy*dy) - d0.w*dx*dy;
            if (!(power > 0.0f || power < d2.y)) {
                float alpha = fminf(ALPHA_MAX_C, d1.y * __expf(power));
                if (alpha >= ALPHA_MIN_C) {
                    float w = Ts * alpha;
                    Crs += w * d1.z;
                    Cgs += w * d1.w;
                    Cbs += w * d2.x;
                    Ts *= (1.0f - alpha);
                }
            }
        }
        scomb[wave*64 + lane] = make_float4(Ts, Crs, Cgs, Cbs);
        __syncthreads();

        if (wave == 0) {
            #pragma unroll
            for (int s = 0; s < NWAVES; ++s) {
                float4 v = scomb[s*64 + lane];
                Crg += Tg * v.y;
                Cgg += Tg * v.z;
                Cbg += Tg * v.w;
                Tg  *= v.x;
            }
        }
        // chunk-level early exit; barrier also protects srec/scomb overwrite
        int alive = __syncthreads_count((tid < 64) && (Tg >= 1e-4f));
        if (alive == 0) break;
    }

    if (wave == 0) {
        float bg0 = bg[0], bg1 = bg[1], bg2 = bg[2];
        int pidx = pyi * IMG_W + pxi;
        out[0*IMG_H*IMG_W + pidx] = Crg + Tg * bg0;
        out[1*IMG_H*IMG_W + pidx] = Cgg + Tg * bg1;
        out[2*IMG_H*IMG_W + pidx] = Cbg + Tg * bg2;
    }
}

extern "C" void kernel_launch(void* const* d_in, const int* in_sizes, int n_in,
                              void* d_out, int out_size, void* d_ws, size_t ws_size,
                              hipStream_t stream) {
    const float* means3D = (const float*)d_in[0];
    // d_in[1] = means2D: unused by the reference output
    const float* opac    = (const float*)d_in[2];
    const float* cols    = (const float*)d_in[3];
    const float* scales  = (const float*)d_in[4];
    const float* rots    = (const float*)d_in[5];
    const float* bg      = (const float*)d_in[6];
    const float* vm      = (const float*)d_in[7];
    float* out = (float*)d_out;

    fused_kernel<<<256, NTHREADS, 0, stream>>>(means3D, opac, cols, scales, rots, bg, vm, out);
}

// Round 7
// 18.003 us; speedup vs baseline: 17.7693x; 1.0872x over previous
//
#include <hip/hip_runtime.h>
#include <math.h>

#define N_G 2048
#define IMG_H 128
#define IMG_W 128

constexpr float FX = 128.0f;          // W / (2*tanfovx)
constexpr float FY = 128.0f;
constexpr float LIMX = 0.65f;         // 1.3 * tanfovx
constexpr float LIMY = 0.65f;
constexpr float ZNEAR_C = 0.2f;
constexpr float ALPHA_MIN_C = 1.0f / 255.0f;
constexpr float ALPHA_MAX_C = 0.99f;

struct VMc { float m[12]; };

// Full per-gaussian math. WANT_COLOR=false instantiations get colors DCE'd.
template <bool WANT_COLOR>
__device__ __forceinline__ void compute_g(
    int i,
    const float* __restrict__ means3D, const float* __restrict__ opac_in,
    const float* __restrict__ cols, const float* __restrict__ scales,
    const float* __restrict__ rots, const VMc& vm,
    float& px, float& py, float& cA, float& cB, float& cC,
    float& op, float& cr, float& cg, float& cb, float& pcut,
    float& tzv, unsigned int& bb)
{
    float mx = means3D[3*i+0], my = means3D[3*i+1], mz = means3D[3*i+2];
    float4 q = *(const float4*)(rots + 4*i);
    float q0 = q.x, q1 = q.y, q2 = q.z, q3 = q.w;
    float qn = 1.0f / sqrtf(q0*q0 + q1*q1 + q2*q2 + q3*q3);
    float r = q0*qn, x = q1*qn, y = q2*qn, z = q3*qn;

    float R00 = 1.0f - 2.0f*(y*y + z*z), R01 = 2.0f*(x*y - r*z), R02 = 2.0f*(x*z + r*y);
    float R10 = 2.0f*(x*y + r*z), R11 = 1.0f - 2.0f*(x*x + z*z), R12 = 2.0f*(y*z - r*x);
    float R20 = 2.0f*(x*z - r*y), R21 = 2.0f*(y*z + r*x), R22 = 1.0f - 2.0f*(x*x + y*y);

    float s0 = scales[3*i+0], s1 = scales[3*i+1], s2 = scales[3*i+2];
    float M00 = R00*s0, M01 = R01*s1, M02 = R02*s2;
    float M10 = R10*s0, M11 = R11*s1, M12 = R12*s2;
    float M20 = R20*s0, M21 = R21*s1, M22 = R22*s2;

    float C00 = M00*M00 + M01*M01 + M02*M02;
    float C01 = M00*M10 + M01*M11 + M02*M12;
    float C02 = M00*M20 + M01*M21 + M02*M22;
    float C11 = M10*M10 + M11*M11 + M12*M12;
    float C12 = M10*M20 + M11*M21 + M12*M22;
    float C22 = M20*M20 + M21*M21 + M22*M22;

    float W00 = vm.m[0], W01 = vm.m[1], W02 = vm.m[2];
    float W10 = vm.m[4], W11 = vm.m[5], W12 = vm.m[6];
    float W20 = vm.m[8], W21 = vm.m[9], W22 = vm.m[10];
    float t0 = W00*mx + W01*my + W02*mz + vm.m[3];
    float t1 = W10*mx + W11*my + W12*mz + vm.m[7];
    float t2 = W20*mx + W21*my + W22*mz + vm.m[11];

    tzv = t2;
    float invz = 1.0f / tzv;
    float txz = fminf(fmaxf(t0*invz, -LIMX), LIMX) * tzv;
    float tyz = fminf(fmaxf(t1*invz, -LIMY), LIMY) * tzv;

    float J00 = FX*invz, J02 = -FX*txz*invz*invz;
    float J11 = FY*invz, J12 = -FY*tyz*invz*invz;

    float T00 = J00*W00 + J02*W20, T01 = J00*W01 + J02*W21, T02 = J00*W02 + J02*W22;
    float T10 = J11*W10 + J12*W20, T11 = J11*W11 + J12*W21, T12 = J11*W12 + J12*W22;

    float U00 = T00*C00 + T01*C01 + T02*C02;
    float U01 = T00*C01 + T01*C11 + T02*C12;
    float U02 = T00*C02 + T01*C12 + T02*C22;
    float U10 = T10*C00 + T11*C01 + T12*C02;
    float U11 = T10*C01 + T11*C11 + T12*C12;
    float U12 = T10*C02 + T11*C12 + T12*C22;

    float a = U00*T00 + U01*T01 + U02*T02 + 0.3f;
    float b = U00*T10 + U01*T11 + U02*T12;
    float c = U10*T10 + U11*T11 + U12*T12 + 0.3f;

    float det = a*c - b*b;
    bool valid = (det > 0.0f) && (tzv > ZNEAR_C);

    if (valid) {
        float invdet = 1.0f / det;
        cA = c * invdet;
        cB = -b * invdet;
        cC = a * invdet;
        px = FX * t0 * invz + (IMG_W - 1) * 0.5f;
        py = FY * t1 * invz + (IMG_H - 1) * 0.5f;
        op = opac_in[i];
        pcut = __logf(ALPHA_MIN_C / op) - 1e-4f;  // conservative margin; exact test after exp
        // ellipse {power >= pcut}: d^T Con d <= -2*pcut; Con^-1 = [[a,b],[b,c]]
        float hx = sqrtf(fmaxf(0.0f, -2.0f * pcut * a));
        float hy = sqrtf(fmaxf(0.0f, -2.0f * pcut * c));
        int ix0 = (int)floorf(px - hx), ix1 = (int)ceilf(px + hx);
        int iy0 = (int)floorf(py - hy), iy1 = (int)ceilf(py + hy);
        if (ix1 < 0 || ix0 > IMG_W-1 || iy1 < 0 || iy0 > IMG_H-1) {
            bb = 0x000000FFu;  // empty
        } else {
            unsigned int X0 = (unsigned int)max(0, ix0), X1 = (unsigned int)min(IMG_W-1, ix1);
            unsigned int Y0 = (unsigned int)max(0, iy0), Y1 = (unsigned int)min(IMG_H-1, iy1);
            bb = X0 | (X1 << 8) | (Y0 << 16) | (Y1 << 24);
        }
    } else {
        px = 0.0f; py = 0.0f; cA = 0.0f; cB = 0.0f; cC = 0.0f;
        op = 0.0f; pcut = 1e30f;
        bb = 0x000000FFu;
    }
    if (WANT_COLOR) {
        cr = cols[3*i+0]; cg = cols[3*i+1]; cb = cols[3*i+2];
    } else {
        cr = 0.0f; cg = 0.0f; cb = 0.0f;
    }
}

#define NTHREADS 512
#define NWAVES 8

// One block per 8x8 tile (16x16 tiles). 512 threads = 8 waves.
// A: all gaussians tz+bbox (redundant per block, parallel across blocks)
// B: per-wave stable ballot compaction of tile hits + cross-wave prefix + keys
// C+D1 (cnt<=512 fast path): per-thread {rank scan || record recompute} fused
// D2: 8-way segmented composite + wave-0 combine
__global__ __launch_bounds__(NTHREADS) void fused_kernel(
    const float* __restrict__ means3D, const float* __restrict__ opac_in,
    const float* __restrict__ cols, const float* __restrict__ scales,
    const float* __restrict__ rots, const float* __restrict__ bg,
    const float* __restrict__ vmp, float* __restrict__ out)
{
    __shared__ float s_tz[N_G];                    // 8 KB
    __shared__ unsigned int s_bb[N_G];             // 8 KB
    __shared__ unsigned short stmp[NWAVES][256];   // 4 KB
    __shared__ unsigned short sidx[N_G];           // 4 KB
    __shared__ unsigned long long skey[N_G + 8];   // 16 KB
    __shared__ unsigned short ssort[N_G];          // 4 KB (sperm in fast path)
    __shared__ float4 srec[NTHREADS*3];            // 24 KB
    __shared__ float4 scomb[NWAVES*64];            // 8 KB
    __shared__ int scnt[NWAVES], soff[NWAVES+1];

    int tid = threadIdx.x;
    int wave = tid >> 6, lane = tid & 63;
    int bx = blockIdx.x & 15, by = blockIdx.x >> 4;
    int tpx0 = bx*8, tpy0 = by*8;

    VMc vm;
    #pragma unroll
    for (int k = 0; k < 12; ++k) vm.m[k] = vmp[k];

    // ---- Phase A: tz + bbox for all gaussians ----
    for (int g = tid; g < N_G; g += NTHREADS) {
        float px,py,cA,cB,cC,op,cr,cg,cb,pcut,tzv; unsigned int bb;
        compute_g<false>(g, means3D, opac_in, cols, scales, rots, vm,
                         px,py,cA,cB,cC,op,cr,cg,cb,pcut,tzv,bb);
        s_tz[g] = tzv;
        s_bb[g] = bb;
    }
    __syncthreads();

    // ---- Phase B: per-wave stable compaction of tile hits ----
    int c = 0;
    #pragma unroll
    for (int r = 0; r < N_G/NTHREADS; ++r) {   // 4 rounds of 64 per wave
        int j = wave*(N_G/NWAVES) + r*64 + lane;
        unsigned int bb = s_bb[j];
        int x0 = bb & 0xFF, x1 = (bb >> 8) & 0xFF;
        int y0 = (bb >> 16) & 0xFF, y1 = (bb >> 24) & 0xFF;
        bool hit = (x0 <= tpx0+7) && (x1 >= tpx0) && (y0 <= tpy0+7) && (y1 >= tpy0);
        unsigned long long m = __ballot(hit);
        if (hit) stmp[wave][c + __popcll(m & ((1ull << lane) - 1ull))] = (unsigned short)j;
        c += __popcll(m);
    }
    if (lane == 0) scnt[wave] = c;
    __syncthreads();
    if (tid == 0) { soff[0] = 0; for (int w = 0; w < NWAVES; ++w) soff[w+1] = soff[w] + scnt[w]; }
    __syncthreads();
    int cnt = soff[NWAVES];
    // copy hits to sidx and build 64-bit sort keys (tz_bits<<16 | idx)
    for (int w = 0; w < NWAVES; ++w) {
        int o = soff[w], n = scnt[w];
        for (int k = tid; k < n; k += NTHREADS) {
            int id = stmp[w][k];
            sidx[o + k] = (unsigned short)id;
            skey[o + k] = ((unsigned long long)__float_as_uint(s_tz[id]) << 16) | (unsigned int)id;
        }
    }
    if (tid < 8) skey[cnt + tid] = ~0ull;   // sentinels for guard-free scan
    __syncthreads();

    int pxi = tpx0 + (lane & 7), pyi = tpy0 + (lane >> 3);
    float fxp = (float)pxi, fyp = (float)pyi;
    float Tg = 1.0f, Crg = 0.0f, Cgg = 0.0f, Cbg = 0.0f;   // wave-0 accumulators

    if (cnt <= NTHREADS) {
        // ---- fast path: fused rank-scan + record recompute, one hit/thread ----
        if (tid < cnt) {
            unsigned long long key_t = skey[tid];
            int g = (int)(key_t & 0xFFFFull);
            // record recompute (VALU) interleaves with key-scan LDS latency
            float px,py,cA,cB,cC,op,cr,cg,cb,pcut,tzv; unsigned int bb;
            compute_g<true>(g, means3D, opac_in, cols, scales, rots, vm,
                            px,py,cA,cB,cC,op,cr,cg,cb,pcut,tzv,bb);
            srec[tid*3+0] = make_float4(px, py, cA, cB);
            srec[tid*3+1] = make_float4(cC, op, cr, cg);
            srec[tid*3+2] = make_float4(cb, pcut, 0.0f, 0.0f);
            int rank = 0;
            int cp = (cnt + 7) & ~7;
            for (int u = 0; u < cp; u += 8) {
                #pragma unroll
                for (int k = 0; k < 8; ++k)
                    rank += (skey[u+k] < key_t) ? 1 : 0;
            }
            ssort[rank] = (unsigned short)tid;   // permutation: sorted pos -> slot
        }
        __syncthreads();

        // ---- segmented composite: wave w does sorted range [w*L,(w+1)*L) ----
        int L = (cnt + NWAVES - 1) / NWAVES;
        int g0 = wave * L, g1 = min(cnt, g0 + L);
        float Ts = 1.0f, Crs = 0.0f, Cgs = 0.0f, Cbs = 0.0f;
        for (int gi = g0; gi < g1; ++gi) {
            int slot = ssort[gi];
            float4 d0 = srec[slot*3+0];
            float4 d1 = srec[slot*3+1];
            float4 d2 = srec[slot*3+2];
            float dx = fxp - d0.x;
            float dy = fyp - d0.y;
            float power = -0.5f*(d0.z*dx*dx + d1.x*dy*dy) - d0.w*dx*dy;
            if (!(power > 0.0f || power < d2.y)) {
                float alpha = fminf(ALPHA_MAX_C, d1.y * __expf(power));
                if (alpha >= ALPHA_MIN_C) {
                    float w = Ts * alpha;
                    Crs += w * d1.z;
                    Cgs += w * d1.w;
                    Cbs += w * d2.x;
                    Ts *= (1.0f - alpha);
                }
            }
        }
        scomb[wave*64 + lane] = make_float4(Ts, Crs, Cgs, Cbs);
        __syncthreads();

        if (wave == 0) {
            #pragma unroll
            for (int s = 0; s < NWAVES; ++s) {
                float4 v = scomb[s*64 + lane];
                Crg += Tg * v.y;
                Cgg += Tg * v.z;
                Cbg += Tg * v.w;
                Tg  *= v.x;
            }
        }
    } else {
        // ---- generic fallback (cnt > 512): thread-parallel rank, chunked D ----
        for (int t = tid; t < cnt; t += NTHREADS) {
            unsigned long long key_t = skey[t];
            int rank = 0;
            int cp = (cnt + 7) & ~7;
            for (int u = 0; u < cp; u += 8) {
                #pragma unroll
                for (int k = 0; k < 8; ++k)
                    rank += (skey[u+k] < key_t) ? 1 : 0;
            }
            ssort[rank] = (unsigned short)(key_t & 0xFFFFull);  // gaussian id
        }
        __syncthreads();

        for (int base = 0; base < cnt; base += NTHREADS) {
            int m = cnt - base; if (m > NTHREADS) m = NTHREADS;
            if (tid < m) {
                int g = ssort[base + tid];
                float px,py,cA,cB,cC,op,cr,cg,cb,pcut,tzv; unsigned int bb;
                compute_g<true>(g, means3D, opac_in, cols, scales, rots, vm,
                                px,py,cA,cB,cC,op,cr,cg,cb,pcut,tzv,bb);
                srec[tid*3+0] = make_float4(px, py, cA, cB);
                srec[tid*3+1] = make_float4(cC, op, cr, cg);
                srec[tid*3+2] = make_float4(cb, pcut, 0.0f, 0.0f);
            }
            __syncthreads();

            int L = (m + NWAVES - 1) / NWAVES;
            int g0 = wave * L, g1 = min(m, g0 + L);
            float Ts = 1.0f, Crs = 0.0f, Cgs = 0.0f, Cbs = 0.0f;
            for (int gi = g0; gi < g1; ++gi) {
                float4 d0 = srec[gi*3+0];
                float4 d1 = srec[gi*3+1];
                float4 d2 = srec[gi*3+2];
                float dx = fxp - d0.x;
                float dy = fyp - d0.y;
                float power = -0.5f*(d0.z*dx*dx + d1.x*dy*dy) - d0.w*dx*dy;
                if (!(power > 0.0f || power < d2.y)) {
                    float alpha = fminf(ALPHA_MAX_C, d1.y * __expf(power));
                    if (alpha >= ALPHA_MIN_C) {
                        float w = Ts * alpha;
                        Crs += w * d1.z;
                        Cgs += w * d1.w;
                        Cbs += w * d2.x;
                        Ts *= (1.0f - alpha);
                    }
                }
            }
            scomb[wave*64 + lane] = make_float4(Ts, Crs, Cgs, Cbs);
            __syncthreads();

            if (wave == 0) {
                #pragma unroll
                for (int s = 0; s < NWAVES; ++s) {
                    float4 v = scomb[s*64 + lane];
                    Crg += Tg * v.y;
                    Cgg += Tg * v.z;
                    Cbg += Tg * v.w;
                    Tg  *= v.x;
                }
            }
            int alive = __syncthreads_count((tid < 64) && (Tg >= 1e-4f));
            if (alive == 0) break;
        }
    }

    if (wave == 0) {
        float bg0 = bg[0], bg1 = bg[1], bg2 = bg[2];
        int pidx = pyi * IMG_W + pxi;
        out[0*IMG_H*IMG_W + pidx] = Crg + Tg * bg0;
        out[1*IMG_H*IMG_W + pidx] = Cgg + Tg * bg1;
        out[2*IMG_H*IMG_W + pidx] = Cbg + Tg * bg2;
    }
}

extern "C" void kernel_launch(void* const* d_in, const int* in_sizes, int n_in,
                              void* d_out, int out_size, void* d_ws, size_t ws_size,
                              hipStream_t stream) {
    const float* means3D = (const float*)d_in[0];
    // d_in[1] = means2D: unused by the reference output
    const float* opac    = (const float*)d_in[2];
    const float* cols    = (const float*)d_in[3];
    const float* scales  = (const float*)d_in[4];
    const float* rots    = (const float*)d_in[5];
    const float* bg      = (const float*)d_in[6];
    const float* vm      = (const float*)d_in[7];
    float* out = (float*)d_out;

    fused_kernel<<<256, NTHREADS, 0, stream>>>(means3D, opac, cols, scales, rots, bg, vm, out);
}